// Round 2
// baseline (16995.593 us; speedup 1.0000x reference)
//
#include <hip/hip_runtime.h>

// Decoder: B=16, T=128, V=32000, E=512, H=1024 (2 LSTM layers), CTX=2048.
// dec_seq: persistent kernel, 256 blocks x 512 threads, own grid barrier.
// fc_gemm: fp32 tiled GEMM [2048x1024]x[32000x1024]^T -> [16][128][32000].

#define NBLK 256

__device__ __forceinline__ float sigf(float x) { return 1.0f / (1.0f + __expf(-x)); }
__device__ __forceinline__ float tanh_(float x) {
  x = fminf(15.0f, fmaxf(-15.0f, x));
  float e = __expf(2.0f * x);
  return (e - 1.0f) / (e + 1.0f);
}

__device__ __forceinline__ void gsync(unsigned* bar) {
  __threadfence();
  __syncthreads();
  if (threadIdx.x == 0) {
    unsigned gen = __hip_atomic_load(bar + 1, __ATOMIC_RELAXED, __HIP_MEMORY_SCOPE_AGENT);
    unsigned arr = __hip_atomic_fetch_add(bar, 1u, __ATOMIC_ACQ_REL, __HIP_MEMORY_SCOPE_AGENT);
    if (arr == (unsigned)(NBLK - 1)) {
      __hip_atomic_store(bar, 0u, __ATOMIC_RELAXED, __HIP_MEMORY_SCOPE_AGENT);
      __hip_atomic_store(bar + 1, gen + 1u, __ATOMIC_RELEASE, __HIP_MEMORY_SCOPE_AGENT);
    } else {
      while (__hip_atomic_load(bar + 1, __ATOMIC_ACQUIRE, __HIP_MEMORY_SCOPE_AGENT) == gen) {
        __builtin_amdgcn_s_sleep(1);
      }
    }
  }
  __syncthreads();
}

// NOTE: function, not macro — macro params named w/x collide with .w/.x members.
__device__ __forceinline__ void dot4(float& a, float4 wv, float4 xv) {
  a = fmaf(wv.x, xv.x, a);
  a = fmaf(wv.y, xv.y, a);
  a = fmaf(wv.z, xv.z, a);
  a = fmaf(wv.w, xv.w, a);
}

#define DECL_ACC                                                        \
  float acc00 = 0.f, acc01 = 0.f, acc02 = 0.f, acc03 = 0.f,             \
        acc10 = 0.f, acc11 = 0.f, acc12 = 0.f, acc13 = 0.f,             \
        acc20 = 0.f, acc21 = 0.f, acc22 = 0.f, acc23 = 0.f,             \
        acc30 = 0.f, acc31 = 0.f, acc32 = 0.f, acc33 = 0.f;

#define KSTEP(p0, p1, p2, p3, K4)                                       \
  {                                                                     \
    const float4 xv0 = *(const float4*)&xls[bq4][(K4)];                 \
    const float4 xv1 = *(const float4*)&xls[bq4 + 1][(K4)];             \
    const float4 xv2 = *(const float4*)&xls[bq4 + 2][(K4)];             \
    const float4 xv3 = *(const float4*)&xls[bq4 + 3][(K4)];             \
    float4 wv;                                                          \
    wv = *(const float4*)(p0);                                          \
    dot4(acc00, wv, xv0); dot4(acc01, wv, xv1);                         \
    dot4(acc02, wv, xv2); dot4(acc03, wv, xv3);                         \
    wv = *(const float4*)(p1);                                          \
    dot4(acc10, wv, xv0); dot4(acc11, wv, xv1);                         \
    dot4(acc12, wv, xv2); dot4(acc13, wv, xv3);                         \
    wv = *(const float4*)(p2);                                          \
    dot4(acc20, wv, xv0); dot4(acc21, wv, xv1);                         \
    dot4(acc22, wv, xv2); dot4(acc23, wv, xv3);                         \
    wv = *(const float4*)(p3);                                          \
    dot4(acc30, wv, xv0); dot4(acc31, wv, xv1);                         \
    dot4(acc32, wv, xv2); dot4(acc33, wv, xv3);                         \
  }

#define RED5(v)                \
  {                            \
    v += __shfl_xor(v, 1);     \
    v += __shfl_xor(v, 2);     \
    v += __shfl_xor(v, 4);     \
    v += __shfl_xor(v, 8);     \
    v += __shfl_xor(v, 16);    \
  }

#define REDUCE_ALL                                                     \
  {                                                                    \
    RED5(acc00) RED5(acc01) RED5(acc02) RED5(acc03)                    \
    RED5(acc10) RED5(acc11) RED5(acc12) RED5(acc13)                    \
    RED5(acc20) RED5(acc21) RED5(acc22) RED5(acc23)                    \
    RED5(acc30) RED5(acc31) RED5(acc32) RED5(acc33)                    \
  }

#define WRITE_GLS                                                                   \
  {                                                                                 \
    if (kc == 0) {                                                                  \
      gls[jq][0][bq4] = acc00; gls[jq][0][bq4 + 1] = acc01;                         \
      gls[jq][0][bq4 + 2] = acc02; gls[jq][0][bq4 + 3] = acc03;                     \
      gls[jq][1][bq4] = acc10; gls[jq][1][bq4 + 1] = acc11;                         \
      gls[jq][1][bq4 + 2] = acc12; gls[jq][1][bq4 + 3] = acc13;                     \
      gls[jq][2][bq4] = acc20; gls[jq][2][bq4 + 1] = acc21;                         \
      gls[jq][2][bq4 + 2] = acc22; gls[jq][2][bq4 + 3] = acc23;                     \
      gls[jq][3][bq4] = acc30; gls[jq][3][bq4 + 1] = acc31;                         \
      gls[jq][3][bq4 + 2] = acc32; gls[jq][3][bq4 + 3] = acc33;                     \
    }                                                                               \
  }

__global__ __launch_bounds__(512, 2) void dec_seq(
    const float* __restrict__ enc_h, const float* __restrict__ enc_c,
    const int* __restrict__ tgt, const float* __restrict__ emb,
    const float* __restrict__ wih0, const float* __restrict__ whh0,
    const float* __restrict__ bih0, const float* __restrict__ bhh0,
    const float* __restrict__ wih1, const float* __restrict__ whh1,
    const float* __restrict__ bih1, const float* __restrict__ bhh1,
    float* __restrict__ h0b, float* __restrict__ h1b,
    float* __restrict__ x1, float* __restrict__ out2,
    unsigned* bar) {
  __shared__ float xls[16][2052];   // [batch][k], padded rows (2052 % 32 == 4)
  __shared__ float gls[4][4][16];   // [gate][dj][b]

  const int tid = threadIdx.x;
  const int wgid = blockIdx.x;          // 0..255 -> 4 hidden units each
  const int kc = tid & 31;              // split-K lane
  const int combo = tid >> 5;           // 0..15
  const int jq = combo >> 2;            // gate 0..3 (i,f,g,o)
  const int bq4 = (combo & 3) * 4;      // batch quad
  const int w4 = wgid * 4;

  const int j0 = jq * 1024 + w4;        // first of this thread's 4 gate rows
  const float* wih0r0 = wih0 + (size_t)(j0 + 0) * 2560;
  const float* wih0r1 = wih0 + (size_t)(j0 + 1) * 2560;
  const float* wih0r2 = wih0 + (size_t)(j0 + 2) * 2560;
  const float* wih0r3 = wih0 + (size_t)(j0 + 3) * 2560;
  const float* whh0r0 = whh0 + (size_t)(j0 + 0) * 1024;
  const float* whh0r1 = whh0 + (size_t)(j0 + 1) * 1024;
  const float* whh0r2 = whh0 + (size_t)(j0 + 2) * 1024;
  const float* whh0r3 = whh0 + (size_t)(j0 + 3) * 1024;
  const float* wih1r0 = wih1 + (size_t)(j0 + 0) * 1024;
  const float* wih1r1 = wih1 + (size_t)(j0 + 1) * 1024;
  const float* wih1r2 = wih1 + (size_t)(j0 + 2) * 1024;
  const float* wih1r3 = wih1 + (size_t)(j0 + 3) * 1024;
  const float* whh1r0 = whh1 + (size_t)(j0 + 0) * 1024;
  const float* whh1r1 = whh1 + (size_t)(j0 + 1) * 1024;
  const float* whh1r2 = whh1 + (size_t)(j0 + 2) * 1024;
  const float* whh1r3 = whh1 + (size_t)(j0 + 3) * 1024;

  // gate-thread persistent state (valid for tid < 64)
  const int gdj = tid >> 4;  // 0..3
  const int gb = tid & 15;   // batch
  float cpA0 = 0.f, cpA1 = 0.f, cpA2 = 0.f, cpA3 = 0.f;
  float cpB0 = 0.f, cpB1 = 0.f, cpB2 = 0.f, cpB3 = 0.f;
  float c0r = 0.f, c1r = 0.f;

  // ---------------- INIT: ctx projection + biases + h/c init ----------------
  // stage ctx[b][k] = enc_h[k>>9][b][k&511] into xls[b][0..2047]
#pragma unroll
  for (int c = 0; c < 16; ++c) {
    int f4 = tid + c * 512;
    int b = f4 >> 9, kq = f4 & 511;
    const float4 v = *(const float4*)(enc_h + (kq >> 7) * 8192 + b * 512 + (kq & 127) * 4);
    *(float4*)&xls[b][kq * 4] = v;
  }
  __syncthreads();
  {
    DECL_ACC
#pragma unroll 4
    for (int i = 0; i < 16; ++i) {
      const int k4 = i * 128 + kc * 4;
      KSTEP(wih0r0 + 512 + k4, wih0r1 + 512 + k4, wih0r2 + 512 + k4, wih0r3 + 512 + k4, k4)
    }
    REDUCE_ALL
    WRITE_GLS
  }
  __syncthreads();
  if (tid < 64) {
    const int jp = w4 + gdj;
    cpA0 = gls[0][gdj][gb] + bih0[jp] + bhh0[jp];
    cpA1 = gls[1][gdj][gb] + bih0[1024 + jp] + bhh0[1024 + jp];
    cpA2 = gls[2][gdj][gb] + bih0[2048 + jp] + bhh0[2048 + jp];
    cpA3 = gls[3][gdj][gb] + bih0[3072 + jp] + bhh0[3072 + jp];
    cpB0 = bih1[jp] + bhh1[jp];
    cpB1 = bih1[1024 + jp] + bhh1[1024 + jp];
    cpB2 = bih1[2048 + jp] + bhh1[2048 + jp];
    cpB3 = bih1[3072 + jp] + bhh1[3072 + jp];
    const int dir = jp >> 9, e = jp & 511;
    c0r = enc_c[dir * 8192 + gb * 512 + e];
    c1r = enc_c[(2 + dir) * 8192 + gb * 512 + e];
    h0b[gb * 1024 + jp] = enc_h[dir * 8192 + gb * 512 + e];
    h1b[gb * 1024 + jp] = enc_h[(2 + dir) * 8192 + gb * 512 + e];
  }
  gsync(bar);

  // ---------------- LAYER 0: 128 steps, K = 512 (emb) + 1024 (h) ----------------
  int cur = 0;
  for (int t = 0; t < 128; ++t) {
#pragma unroll
    for (int c = 0; c < 4; ++c) {
      int f4 = tid + c * 512;
      int b = f4 >> 7, kq = f4 & 127;
      int tok = (t == 0) ? 1 : tgt[b * 128 + (t - 1)];
      const float4 v = *(const float4*)(emb + (size_t)tok * 512 + kq * 4);
      *(float4*)&xls[b][kq * 4] = v;
    }
    const float* hs = h0b + cur * 16384;
#pragma unroll
    for (int c = 0; c < 8; ++c) {
      int f4 = tid + c * 512;
      int b = f4 >> 8, kq = f4 & 255;
      *(float4*)&xls[b][512 + kq * 4] = *(const float4*)(hs + b * 1024 + kq * 4);
    }
    __syncthreads();
    {
      DECL_ACC
#pragma unroll 4
      for (int i = 0; i < 4; ++i) {
        const int k4 = i * 128 + kc * 4;
        KSTEP(wih0r0 + k4, wih0r1 + k4, wih0r2 + k4, wih0r3 + k4, k4)
      }
#pragma unroll 4
      for (int i = 4; i < 12; ++i) {
        const int k4 = i * 128 + kc * 4;
        const int kh = k4 - 512;
        KSTEP(whh0r0 + kh, whh0r1 + kh, whh0r2 + kh, whh0r3 + kh, k4)
      }
      REDUCE_ALL
      WRITE_GLS
    }
    __syncthreads();
    if (tid < 64) {
      const int jp = w4 + gdj;
      float gi = gls[0][gdj][gb] + cpA0;
      float gf = gls[1][gdj][gb] + cpA1;
      float gg = gls[2][gdj][gb] + cpA2;
      float go = gls[3][gdj][gb] + cpA3;
      c0r = sigf(gf) * c0r + sigf(gi) * tanh_(gg);
      float h = sigf(go) * tanh_(c0r);
      h0b[(cur ^ 1) * 16384 + gb * 1024 + jp] = h;
      x1[t * 16384 + gb * 1024 + jp] = h;
    }
    gsync(bar);
    cur ^= 1;
  }

  // ---------------- LAYER 1: 128 steps, K = 1024 (x1) + 1024 (h) ----------------
  int cur2 = 0;
  for (int t = 0; t < 128; ++t) {
    const float* xs = x1 + t * 16384;
#pragma unroll
    for (int c = 0; c < 8; ++c) {
      int f4 = tid + c * 512;
      int b = f4 >> 8, kq = f4 & 255;
      *(float4*)&xls[b][kq * 4] = *(const float4*)(xs + b * 1024 + kq * 4);
    }
    const float* hs = h1b + cur2 * 16384;
#pragma unroll
    for (int c = 0; c < 8; ++c) {
      int f4 = tid + c * 512;
      int b = f4 >> 8, kq = f4 & 255;
      *(float4*)&xls[b][1024 + kq * 4] = *(const float4*)(hs + b * 1024 + kq * 4);
    }
    __syncthreads();
    {
      DECL_ACC
#pragma unroll 4
      for (int i = 0; i < 8; ++i) {
        const int k4 = i * 128 + kc * 4;
        KSTEP(wih1r0 + k4, wih1r1 + k4, wih1r2 + k4, wih1r3 + k4, k4)
      }
#pragma unroll 4
      for (int i = 8; i < 16; ++i) {
        const int k4 = i * 128 + kc * 4;
        const int kh = k4 - 1024;
        KSTEP(whh1r0 + kh, whh1r1 + kh, whh1r2 + kh, whh1r3 + kh, k4)
      }
      REDUCE_ALL
      WRITE_GLS
    }
    __syncthreads();
    if (tid < 64) {
      const int jp = w4 + gdj;
      float gi = gls[0][gdj][gb] + cpB0;
      float gf = gls[1][gdj][gb] + cpB1;
      float gg = gls[2][gdj][gb] + cpB2;
      float go = gls[3][gdj][gb] + cpB3;
      c1r = sigf(gf) * c1r + sigf(gi) * tanh_(gg);
      float h = sigf(go) * tanh_(c1r);
      h1b[(cur2 ^ 1) * 16384 + gb * 1024 + jp] = h;
      out2[(t * 16 + gb) * 1024 + jp] = tanh_(h);
    }
    gsync(bar);
    cur2 ^= 1;
  }
}

// logits[b][t][v] = sum_h out2[t*16+b][h] * fcw[v][h] + fcb[v]
__global__ __launch_bounds__(256, 2) void fc_gemm(
    const float* __restrict__ A, const float* __restrict__ Bw,
    const float* __restrict__ bias, float* __restrict__ C) {
  __shared__ float Asl[32][128];  // [k][m]
  __shared__ float Bsl[32][128];  // [k][n]
  const int tid = threadIdx.x;
  const int m0 = blockIdx.x * 128;  // 16 m-tiles (fast axis -> L2 reuse of Bw)
  const int n0 = blockIdx.y * 128;  // 250 n-tiles
  const int q = tid >> 6;
  const int tx = ((q & 1) << 3) + (tid & 7);
  const int ty = ((q >> 1) << 3) + ((tid >> 3) & 7);
  const int sm = tid >> 1;
  const int sh = (tid & 1) << 4;
  float acc[8][8] = {};
  const float* As = A + (size_t)(m0 + sm) * 1024 + sh;
  const float* Bs = Bw + (size_t)(n0 + sm) * 1024 + sh;

  for (int k0 = 0; k0 < 1024; k0 += 32) {
    float4 a0 = *(const float4*)(As + k0);
    float4 a1 = *(const float4*)(As + k0 + 4);
    float4 a2 = *(const float4*)(As + k0 + 8);
    float4 a3 = *(const float4*)(As + k0 + 12);
    float4 b0 = *(const float4*)(Bs + k0);
    float4 b1 = *(const float4*)(Bs + k0 + 4);
    float4 b2 = *(const float4*)(Bs + k0 + 8);
    float4 b3 = *(const float4*)(Bs + k0 + 12);
    float ta[16], tb[16];
    *(float4*)&ta[0] = a0; *(float4*)&ta[4] = a1; *(float4*)&ta[8] = a2; *(float4*)&ta[12] = a3;
    *(float4*)&tb[0] = b0; *(float4*)&tb[4] = b1; *(float4*)&tb[8] = b2; *(float4*)&tb[12] = b3;
#pragma unroll
    for (int u = 0; u < 16; ++u) {
      Asl[sh + u][sm] = ta[u];
      Bsl[sh + u][sm] = tb[u];
    }
    __syncthreads();
#pragma unroll 8
    for (int kk = 0; kk < 32; ++kk) {
      const float4 A0 = *(const float4*)&Asl[kk][ty * 8];
      const float4 A1 = *(const float4*)&Asl[kk][ty * 8 + 4];
      const float4 B0 = *(const float4*)&Bsl[kk][tx * 8];
      const float4 B1 = *(const float4*)&Bsl[kk][tx * 8 + 4];
      const float av[8] = {A0.x, A0.y, A0.z, A0.w, A1.x, A1.y, A1.z, A1.w};
      const float bv[8] = {B0.x, B0.y, B0.z, B0.w, B1.x, B1.y, B1.z, B1.w};
#pragma unroll
      for (int i = 0; i < 8; ++i)
#pragma unroll
        for (int j = 0; j < 8; ++j) acc[i][j] = fmaf(av[i], bv[j], acc[i][j]);
    }
    __syncthreads();
  }

  const float4 bb0 = *(const float4*)&bias[n0 + tx * 8];
  const float4 bb1 = *(const float4*)&bias[n0 + tx * 8 + 4];
  const float bv[8] = {bb0.x, bb0.y, bb0.z, bb0.w, bb1.x, bb1.y, bb1.z, bb1.w};
#pragma unroll
  for (int i = 0; i < 8; ++i) {
    const int m = m0 + ty * 8 + i;
    float* dst = C + ((size_t)(m & 15) * 128 + (m >> 4)) * 32000 + n0 + tx * 8;
    float4 o0, o1;
    o0.x = acc[i][0] + bv[0]; o0.y = acc[i][1] + bv[1];
    o0.z = acc[i][2] + bv[2]; o0.w = acc[i][3] + bv[3];
    o1.x = acc[i][4] + bv[4]; o1.y = acc[i][5] + bv[5];
    o1.z = acc[i][6] + bv[6]; o1.w = acc[i][7] + bv[7];
    *(float4*)dst = o0;
    *(float4*)(dst + 4) = o1;
  }
}

extern "C" void kernel_launch(void* const* d_in, const int* in_sizes, int n_in,
                              void* d_out, int out_size, void* d_ws, size_t ws_size,
                              hipStream_t stream) {
  const float* enc_h = (const float*)d_in[0];
  const float* enc_c = (const float*)d_in[1];
  const int* tgt = (const int*)d_in[2];
  const float* emb = (const float*)d_in[3];
  const float* wih0 = (const float*)d_in[4];
  const float* whh0 = (const float*)d_in[5];
  const float* bih0 = (const float*)d_in[6];
  const float* bhh0 = (const float*)d_in[7];
  const float* wih1 = (const float*)d_in[8];
  const float* whh1 = (const float*)d_in[9];
  const float* bih1 = (const float*)d_in[10];
  const float* bhh1 = (const float*)d_in[11];
  const float* fcw = (const float*)d_in[12];
  const float* fcb = (const float*)d_in[13];
  float* logits = (float*)d_out;

  unsigned* bar = (unsigned*)d_ws;
  float* wsf = (float*)((char*)d_ws + 256);
  float* h0b = wsf;                   // 2 * 16384
  float* h1b = wsf + 32768;           // 2 * 16384
  float* x1 = wsf + 65536;            // 128 * 16384
  float* out2 = x1 + 2097152;         // 128 * 16384

  hipMemsetAsync(d_ws, 0, 8, stream);  // barrier counter+generation
  dec_seq<<<NBLK, 512, 0, stream>>>(enc_h, enc_c, tgt, emb, wih0, whh0, bih0, bhh0,
                                    wih1, whh1, bih1, bhh1, h0b, h1b, x1, out2, bar);
  fc_gemm<<<dim3(16, 250), 256, 0, stream>>>(out2, fcw, fcb, logits);
}